// Round 4
// baseline (304.828 us; speedup 1.0000x reference)
//
#include <hip/hip_runtime.h>

typedef unsigned short u16;
typedef unsigned int u32;
typedef __bf16 bf16x8 __attribute__((ext_vector_type(8)));
typedef float f32x4 __attribute__((ext_vector_type(4)));
typedef u16 u16x8 __attribute__((ext_vector_type(8)));
typedef u32 u32x2 __attribute__((ext_vector_type(2)));

#define NB 64
#define NN 512
#define NH 12
#define HD 32
#define DIM 384

static constexpr size_t QWS = (size_t)NB * NH * NN * HD;  // bf16 elems per tensor
#define LOG2E 1.4426950408889634f
#define QSCALE 0.25503486f   // (1/sqrt(32)) * log2(e)

__device__ __forceinline__ u16 f2bf(float f) {
  __bf16 b = (__bf16)f;
  union { __bf16 b; u16 u; } v; v.b = b;
  return v.u;
}
__device__ __forceinline__ float lo16f(u32 w) {
  union { u32 u; float f; } v; v.u = w << 16;
  return v.f;
}
__device__ __forceinline__ float hi16f(u32 w) {
  union { u32 u; float f; } v; v.u = w & 0xffff0000u;
  return v.f;
}

// ---------------------------------------------------------------------------
// Kernel 1: expand relative-position bias to [H][N][N] bf16, pre-scaled log2e
// ---------------------------------------------------------------------------
__global__ __launch_bounds__(256) void bias_expand_k(const float* __restrict__ table,
                                                     const int* __restrict__ rel,
                                                     u16* __restrict__ be) {
  int t = blockIdx.x * 256 + threadIdx.x;
  int idx = rel[t];
  const float* row = table + (size_t)idx * NH;
#pragma unroll
  for (int h = 0; h < NH; ++h)
    be[(size_t)h * (NN * NN) + t] = f2bf(row[h] * LOG2E);
}

// ---------------------------------------------------------------------------
// Kernel 2: fused QKV projection GEMM (q gets (x+qb)*QSCALE folded in).
// ---------------------------------------------------------------------------
__global__ __launch_bounds__(256) void qkv_proj_k(const float* __restrict__ x1,
                                                  const float* __restrict__ x2,
                                                  const float* __restrict__ Wq,
                                                  const float* __restrict__ Wkv,
                                                  const float* __restrict__ qb,
                                                  const float* __restrict__ vb,
                                                  u16* __restrict__ q_ws,
                                                  u16* __restrict__ k_ws,
                                                  u16* __restrict__ v_ws) {
  const int g = blockIdx.x;                    // 0..2303
  const int v = (g & 7) * 288 + (g >> 3);      // chunk per XCD
  const int ct = v % 9;
  const int m0 = (v / 9) * 128;
  const int j0 = ct * 128;
  const float* A;
  const float* W;
  int type;
  if (ct < 3)      { A = x1; W = Wq  + (size_t)j0 * DIM;         type = 0; }
  else if (ct < 6) { A = x2; W = Wkv + (size_t)(j0 - 384) * DIM; type = 1; }
  else             { A = x2; W = Wkv + (size_t)(j0 - 384) * DIM; type = 2; }

  __shared__ u16 As[128][72];
  __shared__ u16 Bs[128][72];

  const int tid = threadIdx.x;
  const int lane = tid & 63, wid = tid >> 6;
  const int wm = (wid >> 1) * 64, wn = (wid & 1) * 64;
  const int lg = lane >> 4, lr = lane & 15;
  const int srow = tid >> 3;
  const int scol = (tid & 7) * 8;

  f32x4 acc[4][4] = {};

  for (int k0 = 0; k0 < DIM; k0 += 64) {
    __syncthreads();
#pragma unroll
    for (int rr = 0; rr < 4; ++rr) {
      int r = srow + rr * 32;
      const float* src = A + (size_t)(m0 + r) * DIM + k0 + scol;
      float4 f0 = *(const float4*)src;
      float4 f1 = *(const float4*)(src + 4);
      u16x8 tmp = {f2bf(f0.x), f2bf(f0.y), f2bf(f0.z), f2bf(f0.w),
                   f2bf(f1.x), f2bf(f1.y), f2bf(f1.z), f2bf(f1.w)};
      *(u16x8*)&As[r][scol] = tmp;
      const float* srcB = W + (size_t)r * DIM + k0 + scol;
      float4 g0 = *(const float4*)srcB;
      float4 g1 = *(const float4*)(srcB + 4);
      u16x8 tmpB = {f2bf(g0.x), f2bf(g0.y), f2bf(g0.z), f2bf(g0.w),
                    f2bf(g1.x), f2bf(g1.y), f2bf(g1.z), f2bf(g1.w)};
      *(u16x8*)&Bs[r][scol] = tmpB;
    }
    __syncthreads();
#pragma unroll
    for (int kk = 0; kk < 2; ++kk) {
      bf16x8 af[4], bfv[4];
#pragma unroll
      for (int mf = 0; mf < 4; ++mf)
        af[mf] = *(const bf16x8*)&As[wm + mf * 16 + lr][kk * 32 + lg * 8];
#pragma unroll
      for (int nf = 0; nf < 4; ++nf)
        bfv[nf] = *(const bf16x8*)&Bs[wn + nf * 16 + lr][kk * 32 + lg * 8];
#pragma unroll
      for (int mf = 0; mf < 4; ++mf)
#pragma unroll
        for (int nf = 0; nf < 4; ++nf)
          acc[mf][nf] = __builtin_amdgcn_mfma_f32_16x16x32_bf16(af[mf], bfv[nf], acc[mf][nf], 0, 0, 0);
    }
  }

  const int b = m0 >> 9;
  u16* dst = (type == 0) ? q_ws : (type == 1 ? k_ws : v_ws);
  const float scale = (type == 0) ? QSCALE : 1.0f;
#pragma unroll
  for (int nf = 0; nf < 4; ++nf) {
    int j = j0 + wn + nf * 16 + lr;
    int jj = j - ((type == 0) ? 0 : (type == 1 ? 384 : 768));
    float bv = (type == 0) ? qb[jj] : (type == 2 ? vb[jj] : 0.0f);
    int h = jj >> 5, d = jj & 31;
    u16* dcol = dst + (((size_t)b * NH + h) * NN) * HD + d;
#pragma unroll
    for (int mf = 0; mf < 4; ++mf) {
      int nbase = (m0 & 511) + wm + mf * 16 + lg * 4;
#pragma unroll
      for (int r = 0; r < 4; ++r) {
        float val = (acc[mf][nf][r] + bv) * scale;
        dcol[(size_t)(nbase + r) * HD] = f2bf(val);
      }
    }
  }
}

// ---------------------------------------------------------------------------
// Kernel 3: attention, swapped QK + k-permuted V (zero-shuffle PV).
//   K fragments read straight from global (coalesced 1KB/wave, L1/L2-hit);
//   only V^T (permuted) lives in LDS -> 33 KB -> 3-4 blocks/CU.
//   exp via __builtin_amdgcn_exp2f (single v_exp_f32); bias unpacked from
//   u32 words with shift/and (1 VALU per element).
// ---------------------------------------------------------------------------
__global__ __launch_bounds__(512, 6) void attn_k(const u16* __restrict__ qw,
                                                 const u16* __restrict__ kw,
                                                 const u16* __restrict__ vw,
                                                 const u16* __restrict__ be,
                                                 float* __restrict__ out) {
  const int g = blockIdx.x;                 // 0..767
  const int vv = (g & 7) * 96 + (g >> 3);   // chunk per XCD
  const int h = vv >> 6, b = vv & 63;
  const size_t base = ((size_t)b * NH + h) * NN * HD;
  const u16* Q = qw + base;
  const u16* K = kw + base;
  const u16* V = vw + base;
  const u16* bias = be + (size_t)h * NN * NN;

  __shared__ u16 Vtp[HD][520];   // [d][k-permuted], 1040B stride

  const int tid = threadIdx.x;
  const int lane = tid & 63, w = tid >> 6;
  const int lg = lane >> 4, lr = lane & 15;
  const int q0 = w * 64;

  // Q fragments (B-operand of QK^T)
  bf16x8 qf[4];
#pragma unroll
  for (int mf = 0; mf < 4; ++mf)
    qf[mf] = *(const bf16x8*)&Q[(q0 + mf * 16 + lr) * HD + lg * 8];

  // stage V transposed with permuted key columns
  for (int c = tid; c < 2048; c += 512) {
    int row = c >> 2, part = (c & 3) * 8;
    u16x8 vld = *(const u16x8*)&V[row * HD + part];
    int kk = row & 31;
    int col = (row & ~31) + ((kk >> 2) & 3) * 8 + (kk >> 4) * 4 + (kk & 3);
#pragma unroll
    for (int j = 0; j < 8; ++j) Vtp[part + j][col] = vld[j];
  }
  __syncthreads();

  // per-lane bases
  const u32* brow = (const u32*)bias + (size_t)(q0 + lr) * (NN / 2) + lg * 2;
  const u16* kfp = K + lr * HD + lg * 8;

  f32x4 accOT[4][2] = {};
  float lsum[4] = {0.f, 0.f, 0.f, 0.f};
  const f32x4 zero = {0.f, 0.f, 0.f, 0.f};

  for (int kt = 0; kt < 16; ++kt) {
    const int k0 = kt * 32;
    bf16x8 kf0 = *(const bf16x8*)(kfp + (size_t)k0 * HD);
    bf16x8 kf1 = *(const bf16x8*)(kfp + (size_t)(k0 + 16) * HD);
    bf16x8 vp0 = *(const bf16x8*)&Vtp[lr][k0 + lg * 8];
    bf16x8 vp1 = *(const bf16x8*)&Vtp[16 + lr][k0 + lg * 8];
#pragma unroll
    for (int mf = 0; mf < 4; ++mf) {
      f32x4 s0 = __builtin_amdgcn_mfma_f32_16x16x32_bf16(kf0, qf[mf], zero, 0, 0, 0);
      f32x4 s1 = __builtin_amdgcn_mfma_f32_16x16x32_bf16(kf1, qf[mf], zero, 0, 0, 0);
      const u32* bq = brow + mf * 16 * (NN / 2);
      u32x2 w0 = *(const u32x2*)(bq + (k0 >> 1));
      u32x2 w1 = *(const u32x2*)(bq + (k0 >> 1) + 8);
      float p0[4], p1[4];
      p0[0] = __builtin_amdgcn_exp2f(s0[0] + lo16f(w0.x));
      p0[1] = __builtin_amdgcn_exp2f(s0[1] + hi16f(w0.x));
      p0[2] = __builtin_amdgcn_exp2f(s0[2] + lo16f(w0.y));
      p0[3] = __builtin_amdgcn_exp2f(s0[3] + hi16f(w0.y));
      p1[0] = __builtin_amdgcn_exp2f(s1[0] + lo16f(w1.x));
      p1[1] = __builtin_amdgcn_exp2f(s1[1] + hi16f(w1.x));
      p1[2] = __builtin_amdgcn_exp2f(s1[2] + lo16f(w1.y));
      p1[3] = __builtin_amdgcn_exp2f(s1[3] + hi16f(w1.y));
      lsum[mf] += ((p0[0] + p0[1]) + (p0[2] + p0[3])) +
                  ((p1[0] + p1[1]) + (p1[2] + p1[3]));
      bf16x8 pv = {(__bf16)p0[0], (__bf16)p0[1], (__bf16)p0[2], (__bf16)p0[3],
                   (__bf16)p1[0], (__bf16)p1[1], (__bf16)p1[2], (__bf16)p1[3]};
      accOT[mf][0] = __builtin_amdgcn_mfma_f32_16x16x32_bf16(vp0, pv, accOT[mf][0], 0, 0, 0);
      accOT[mf][1] = __builtin_amdgcn_mfma_f32_16x16x32_bf16(vp1, pv, accOT[mf][1], 0, 0, 0);
    }
  }

  // reduce row-sums across lg groups (bits 4,5 of lane)
  float linv[4];
#pragma unroll
  for (int mf = 0; mf < 4; ++mf) {
    float s = lsum[mf];
    s += __shfl_xor(s, 16, 64);
    s += __shfl_xor(s, 32, 64);
    linv[mf] = 1.0f / s;
  }

  // O^T[d = nf*16 + lg*4 + r][q = q0 + mf*16 + lr] -> out[b][q][h*32+d], float4
  float* outp = out + ((size_t)b * NN) * DIM + h * HD;
#pragma unroll
  for (int mf = 0; mf < 4; ++mf) {
    int q = q0 + mf * 16 + lr;
#pragma unroll
    for (int nf = 0; nf < 2; ++nf) {
      float4 o = {accOT[mf][nf][0] * linv[mf], accOT[mf][nf][1] * linv[mf],
                  accOT[mf][nf][2] * linv[mf], accOT[mf][nf][3] * linv[mf]};
      *(float4*)&outp[(size_t)q * DIM + nf * 16 + lg * 4] = o;
    }
  }
}

// ---------------------------------------------------------------------------
extern "C" void kernel_launch(void* const* d_in, const int* in_sizes, int n_in,
                              void* d_out, int out_size, void* d_ws, size_t ws_size,
                              hipStream_t stream) {
  const float* x1    = (const float*)d_in[0];
  const float* x2    = (const float*)d_in[1];
  const float* Wq    = (const float*)d_in[2];
  const float* Wkv   = (const float*)d_in[3];
  const float* qb    = (const float*)d_in[4];
  const float* vb    = (const float*)d_in[5];
  const float* table = (const float*)d_in[6];
  const int*   rel   = (const int*)d_in[7];
  float* out = (float*)d_out;

  u16* ws   = (u16*)d_ws;
  u16* q_ws = ws;
  u16* k_ws = ws + QWS;
  u16* v_ws = ws + 2 * QWS;
  u16* be   = ws + 3 * QWS;

  bias_expand_k<<<(NN * NN) / 256, 256, 0, stream>>>(table, rel, be);
  qkv_proj_k<<<2304, 256, 0, stream>>>(x1, x2, Wq, Wkv, qb, vb, q_ws, k_ws, v_ws);
  attn_k<<<NB * NH, 512, 0, stream>>>(q_ws, k_ws, v_ws, be, out);
}

// Round 5
// 165.278 us; speedup vs baseline: 1.8443x; 1.8443x over previous
//
#include <hip/hip_runtime.h>

typedef unsigned short u16;
typedef unsigned int u32;
typedef __bf16 bf16x8 __attribute__((ext_vector_type(8)));
typedef float f32x4 __attribute__((ext_vector_type(4)));
typedef u16 u16x8 __attribute__((ext_vector_type(8)));
typedef u32 u32x2 __attribute__((ext_vector_type(2)));

#define NB 64
#define NN 512
#define NH 12
#define HD 32
#define DIM 384

static constexpr size_t QWS = (size_t)NB * NH * NN * HD;  // bf16 elems per tensor
#define LOG2E 1.4426950408889634f
#define QSCALE 0.25503486f   // (1/sqrt(32)) * log2(e)

__device__ __forceinline__ u16 f2bf(float f) {
  __bf16 b = (__bf16)f;
  union { __bf16 b; u16 u; } v; v.b = b;
  return v.u;
}
__device__ __forceinline__ float lo16f(u32 w) {
  union { u32 u; float f; } v; v.u = w << 16;
  return v.f;
}
__device__ __forceinline__ float hi16f(u32 w) {
  union { u32 u; float f; } v; v.u = w & 0xffff0000u;
  return v.f;
}

// ---------------------------------------------------------------------------
// Kernel 1: expand relative-position bias to [H][N][N] bf16, pre-scaled log2e
// ---------------------------------------------------------------------------
__global__ __launch_bounds__(256) void bias_expand_k(const float* __restrict__ table,
                                                     const int* __restrict__ rel,
                                                     u16* __restrict__ be) {
  int t = blockIdx.x * 256 + threadIdx.x;
  int idx = rel[t];
  const float* row = table + (size_t)idx * NH;
#pragma unroll
  for (int h = 0; h < NH; ++h)
    be[(size_t)h * (NN * NN) + t] = f2bf(row[h] * LOG2E);
}

// ---------------------------------------------------------------------------
// Kernel 2: fused QKV projection GEMM (q gets (x+qb)*QSCALE folded in).
// ---------------------------------------------------------------------------
__global__ __launch_bounds__(256) void qkv_proj_k(const float* __restrict__ x1,
                                                  const float* __restrict__ x2,
                                                  const float* __restrict__ Wq,
                                                  const float* __restrict__ Wkv,
                                                  const float* __restrict__ qb,
                                                  const float* __restrict__ vb,
                                                  u16* __restrict__ q_ws,
                                                  u16* __restrict__ k_ws,
                                                  u16* __restrict__ v_ws) {
  const int g = blockIdx.x;                    // 0..2303
  const int v = (g & 7) * 288 + (g >> 3);      // chunk per XCD
  const int ct = v % 9;
  const int m0 = (v / 9) * 128;
  const int j0 = ct * 128;
  const float* A;
  const float* W;
  int type;
  if (ct < 3)      { A = x1; W = Wq  + (size_t)j0 * DIM;         type = 0; }
  else if (ct < 6) { A = x2; W = Wkv + (size_t)(j0 - 384) * DIM; type = 1; }
  else             { A = x2; W = Wkv + (size_t)(j0 - 384) * DIM; type = 2; }

  __shared__ u16 As[128][72];
  __shared__ u16 Bs[128][72];

  const int tid = threadIdx.x;
  const int lane = tid & 63, wid = tid >> 6;
  const int wm = (wid >> 1) * 64, wn = (wid & 1) * 64;
  const int lg = lane >> 4, lr = lane & 15;
  const int srow = tid >> 3;
  const int scol = (tid & 7) * 8;

  f32x4 acc[4][4] = {};

  for (int k0 = 0; k0 < DIM; k0 += 64) {
    __syncthreads();
#pragma unroll
    for (int rr = 0; rr < 4; ++rr) {
      int r = srow + rr * 32;
      const float* src = A + (size_t)(m0 + r) * DIM + k0 + scol;
      float4 f0 = *(const float4*)src;
      float4 f1 = *(const float4*)(src + 4);
      u16x8 tmp = {f2bf(f0.x), f2bf(f0.y), f2bf(f0.z), f2bf(f0.w),
                   f2bf(f1.x), f2bf(f1.y), f2bf(f1.z), f2bf(f1.w)};
      *(u16x8*)&As[r][scol] = tmp;
      const float* srcB = W + (size_t)r * DIM + k0 + scol;
      float4 g0 = *(const float4*)srcB;
      float4 g1 = *(const float4*)(srcB + 4);
      u16x8 tmpB = {f2bf(g0.x), f2bf(g0.y), f2bf(g0.z), f2bf(g0.w),
                    f2bf(g1.x), f2bf(g1.y), f2bf(g1.z), f2bf(g1.w)};
      *(u16x8*)&Bs[r][scol] = tmpB;
    }
    __syncthreads();
#pragma unroll
    for (int kk = 0; kk < 2; ++kk) {
      bf16x8 af[4], bfv[4];
#pragma unroll
      for (int mf = 0; mf < 4; ++mf)
        af[mf] = *(const bf16x8*)&As[wm + mf * 16 + lr][kk * 32 + lg * 8];
#pragma unroll
      for (int nf = 0; nf < 4; ++nf)
        bfv[nf] = *(const bf16x8*)&Bs[wn + nf * 16 + lr][kk * 32 + lg * 8];
#pragma unroll
      for (int mf = 0; mf < 4; ++mf)
#pragma unroll
        for (int nf = 0; nf < 4; ++nf)
          acc[mf][nf] = __builtin_amdgcn_mfma_f32_16x16x32_bf16(af[mf], bfv[nf], acc[mf][nf], 0, 0, 0);
    }
  }

  const int b = m0 >> 9;
  u16* dst = (type == 0) ? q_ws : (type == 1 ? k_ws : v_ws);
  const float scale = (type == 0) ? QSCALE : 1.0f;
#pragma unroll
  for (int nf = 0; nf < 4; ++nf) {
    int j = j0 + wn + nf * 16 + lr;
    int jj = j - ((type == 0) ? 0 : (type == 1 ? 384 : 768));
    float bv = (type == 0) ? qb[jj] : (type == 2 ? vb[jj] : 0.0f);
    int h = jj >> 5, d = jj & 31;
    u16* dcol = dst + (((size_t)b * NH + h) * NN) * HD + d;
#pragma unroll
    for (int mf = 0; mf < 4; ++mf) {
      int nbase = (m0 & 511) + wm + mf * 16 + lg * 4;
#pragma unroll
      for (int r = 0; r < 4; ++r) {
        float val = (acc[mf][nf][r] + bv) * scale;
        dcol[(size_t)(nbase + r) * HD] = f2bf(val);
      }
    }
  }
}

// ---------------------------------------------------------------------------
// Kernel 3: attention, swapped QK + k-permuted V (zero-shuffle PV).
//   - bias pre-loaded as the MFMA C operand (no adds)
//   - row-sums via an extra ones-MFMA on the idle matrix pipe (no VALU adds,
//     no end-of-loop shuffle reduce: every lane holds its q's full sum)
//   - exp via __builtin_amdgcn_exp2f (single v_exp_f32)
//   K,V^T in LDS (74KB, 2 blocks/CU), launch_bounds (512,4): VGPR cap 128.
// ---------------------------------------------------------------------------
__global__ __launch_bounds__(512, 4) void attn_k(const u16* __restrict__ qw,
                                                 const u16* __restrict__ kw,
                                                 const u16* __restrict__ vw,
                                                 const u16* __restrict__ be,
                                                 float* __restrict__ out) {
  const int g = blockIdx.x;                 // 0..767
  const int vv = (g & 7) * 96 + (g >> 3);   // chunk per XCD
  const int h = vv >> 6, b = vv & 63;
  const size_t base = ((size_t)b * NH + h) * NN * HD;
  const u16* Q = qw + base;
  const u16* K = kw + base;
  const u16* V = vw + base;
  const u16* bias = be + (size_t)h * NN * NN;

  __shared__ u16 Ks[NN][40];     // [k][d], 80B stride
  __shared__ u16 Vtp[HD][520];   // [d][k-permuted], 1040B stride

  const int tid = threadIdx.x;
  const int lane = tid & 63, w = tid >> 6;
  const int lg = lane >> 4, lr = lane & 15;
  const int q0 = w * 64;

  // Q fragments (B-operand of QK^T)
  bf16x8 qf[4];
#pragma unroll
  for (int mf = 0; mf < 4; ++mf)
    qf[mf] = *(const bf16x8*)&Q[(q0 + mf * 16 + lr) * HD + lg * 8];

  // stage K row-major; V transposed with permuted key columns
  for (int c = tid; c < 2048; c += 512) {
    int row = c >> 2, part = (c & 3) * 8;
    *(u16x8*)&Ks[row][part] = *(const u16x8*)&K[row * HD + part];
    u16x8 vld = *(const u16x8*)&V[row * HD + part];
    int kk = row & 31;
    int col = (row & ~31) + ((kk >> 2) & 3) * 8 + (kk >> 4) * 4 + (kk & 3);
#pragma unroll
    for (int j = 0; j < 8; ++j) Vtp[part + j][col] = vld[j];
  }
  __syncthreads();

  const u32* brow = (const u32*)bias + (size_t)(q0 + lr) * (NN / 2) + lg * 2;

  // all-ones A fragment for the row-sum MFMA
  bf16x8 ones;
#pragma unroll
  for (int j = 0; j < 8; ++j) ones[j] = (__bf16)1.0f;

  f32x4 accOT[4][2] = {};
  f32x4 accSum[4] = {};

  for (int kt = 0; kt < 16; ++kt) {
    const int k0 = kt * 32;
    bf16x8 kf0 = *(const bf16x8*)&Ks[k0 + lr][lg * 8];
    bf16x8 kf1 = *(const bf16x8*)&Ks[k0 + 16 + lr][lg * 8];
    bf16x8 vp0 = *(const bf16x8*)&Vtp[lr][k0 + lg * 8];
    bf16x8 vp1 = *(const bf16x8*)&Vtp[16 + lr][k0 + lg * 8];
#pragma unroll
    for (int mf = 0; mf < 4; ++mf) {
      const u32* bq = brow + mf * 16 * (NN / 2) + (k0 >> 1);
      u32x2 w0 = *(const u32x2*)bq;
      u32x2 w1 = *(const u32x2*)(bq + 8);
      f32x4 c0 = {lo16f(w0.x), hi16f(w0.x), lo16f(w0.y), hi16f(w0.y)};
      f32x4 c1 = {lo16f(w1.x), hi16f(w1.x), lo16f(w1.y), hi16f(w1.y)};
      f32x4 s0 = __builtin_amdgcn_mfma_f32_16x16x32_bf16(kf0, qf[mf], c0, 0, 0, 0);
      f32x4 s1 = __builtin_amdgcn_mfma_f32_16x16x32_bf16(kf1, qf[mf], c1, 0, 0, 0);
      float p0[4], p1[4];
#pragma unroll
      for (int r = 0; r < 4; ++r) {
        p0[r] = __builtin_amdgcn_exp2f(s0[r]);
        p1[r] = __builtin_amdgcn_exp2f(s1[r]);
      }
      bf16x8 pv = {(__bf16)p0[0], (__bf16)p0[1], (__bf16)p0[2], (__bf16)p0[3],
                   (__bf16)p1[0], (__bf16)p1[1], (__bf16)p1[2], (__bf16)p1[3]};
      accOT[mf][0] = __builtin_amdgcn_mfma_f32_16x16x32_bf16(vp0, pv, accOT[mf][0], 0, 0, 0);
      accOT[mf][1] = __builtin_amdgcn_mfma_f32_16x16x32_bf16(vp1, pv, accOT[mf][1], 0, 0, 0);
      accSum[mf]   = __builtin_amdgcn_mfma_f32_16x16x32_bf16(ones, pv, accSum[mf], 0, 0, 0);
    }
  }

  // every lane already holds the full row-sum for its q (all 16 sum-rows equal)
  float linv[4];
#pragma unroll
  for (int mf = 0; mf < 4; ++mf) linv[mf] = 1.0f / accSum[mf][0];

  // O^T[d = nf*16 + lg*4 + r][q = q0 + mf*16 + lr] -> out[b][q][h*32+d], float4
  float* outp = out + ((size_t)b * NN) * DIM + h * HD;
#pragma unroll
  for (int mf = 0; mf < 4; ++mf) {
    int q = q0 + mf * 16 + lr;
#pragma unroll
    for (int nf = 0; nf < 2; ++nf) {
      float4 o = {accOT[mf][nf][0] * linv[mf], accOT[mf][nf][1] * linv[mf],
                  accOT[mf][nf][2] * linv[mf], accOT[mf][nf][3] * linv[mf]};
      *(float4*)&outp[(size_t)q * DIM + nf * 16 + lg * 4] = o;
    }
  }
}

// ---------------------------------------------------------------------------
extern "C" void kernel_launch(void* const* d_in, const int* in_sizes, int n_in,
                              void* d_out, int out_size, void* d_ws, size_t ws_size,
                              hipStream_t stream) {
  const float* x1    = (const float*)d_in[0];
  const float* x2    = (const float*)d_in[1];
  const float* Wq    = (const float*)d_in[2];
  const float* Wkv   = (const float*)d_in[3];
  const float* qb    = (const float*)d_in[4];
  const float* vb    = (const float*)d_in[5];
  const float* table = (const float*)d_in[6];
  const int*   rel   = (const int*)d_in[7];
  float* out = (float*)d_out;

  u16* ws   = (u16*)d_ws;
  u16* q_ws = ws;
  u16* k_ws = ws + QWS;
  u16* v_ws = ws + 2 * QWS;
  u16* be   = ws + 3 * QWS;

  bias_expand_k<<<(NN * NN) / 256, 256, 0, stream>>>(table, rel, be);
  qkv_proj_k<<<2304, 256, 0, stream>>>(x1, x2, Wq, Wkv, qb, vb, q_ws, k_ws, v_ws);
  attn_k<<<NB * NH, 512, 0, stream>>>(q_ws, k_ws, v_ws, be, out);
}